// Round 15
// baseline (176.623 us; speedup 1.0000x reference)
//
#include <hip/hip_runtime.h>
#include <hip/hip_bf16.h>

typedef __attribute__((ext_vector_type(8))) short bf16x8;
typedef __attribute__((ext_vector_type(4))) float f32x4;
using bf16 = __hip_bfloat16;

#define NTOK 4096
#define EPS_LN 1e-5f
#define QSCL 0.1803368801111244f  // 0.125 * log2(e): softmax in exp2 domain

enum { EPI_QKV = 1, EPI_RELU_BF16 = 2 };

#define LGKM0 asm volatile("s_waitcnt lgkmcnt(0)" ::: "memory")
#define SCHED0 __builtin_amdgcn_sched_barrier(0)
#define VM0 asm volatile("s_waitcnt vmcnt(0)" ::: "memory")
#define DSRO(dst, ad, off) \
  asm volatile("ds_read_b128 %0, %1 offset:" #off : "=v"(dst) : "v"(ad))

__device__ inline void gload_lds16(const void* g, void* l) {
  __builtin_amdgcn_global_load_lds(
      (const __attribute__((address_space(1))) char*)g,
      (__attribute__((address_space(3))) char*)l, 16, 0, 0);
}

__device__ inline unsigned ldsoff(const void* p) {
  return (unsigned)(size_t)(const __attribute__((address_space(3))) char*)p;
}

__device__ inline unsigned short f2bfu(float x) {
  bf16 h = __float2bfloat16(x);
  return __builtin_bit_cast(unsigned short, h);
}
__device__ inline bf16 to_bf16(float v) { return __float2bfloat16(v); }
__device__ inline bf16 to_bf16(bf16 v) { return v; }

__device__ inline unsigned cvtpk(float lo, float hi) {
  unsigned r;
  asm volatile("v_cvt_pk_bf16_f32 %0, %1, %2" : "=v"(r) : "v"(lo), "v"(hi));
  return r;
}
__device__ inline float bu2f(unsigned short u) {
  unsigned v = (unsigned)u << 16;
  return __builtin_bit_cast(float, v);
}

// ---------------- prep kernels ----------------

__global__ __launch_bounds__(256) void cvt_bf16_kernel(const float* __restrict__ src,
                                                       bf16* __restrict__ dst, int n4) {
  int i = blockIdx.x * 256 + threadIdx.x;
  if (i >= n4) return;
  float4 v = ((const float4*)src)[i];
  ushort4 o;
  o.x = f2bfu(v.x); o.y = f2bfu(v.y); o.z = f2bfu(v.z); o.w = f2bfu(v.w);
  ((ushort4*)dst)[i] = o;
}

template <typename ST>
__global__ __launch_bounds__(256) void transpose_cvt(const ST* __restrict__ src,
                                                     bf16* __restrict__ dst, int R, int C) {
  __shared__ bf16 tile[32][33];
  int o = blockIdx.z;
  int r0 = blockIdx.y * 32, c0 = blockIdx.x * 32;
  int tx = threadIdx.x & 31, ty = threadIdx.x >> 5;
  const ST* s = src + (size_t)o * R * C;
  bf16* d = dst + (size_t)o * R * C;
#pragma unroll
  for (int i = 0; i < 32; i += 8)
    tile[ty + i][tx] = to_bf16(s[(size_t)(r0 + ty + i) * C + (c0 + tx)]);
  __syncthreads();
#pragma unroll
  for (int i = 0; i < 32; i += 8)
    d[(size_t)(c0 + ty + i) * R + (r0 + tx)] = tile[tx][ty + i];
}

__global__ __launch_bounds__(256) void pack_bias_kernel(const float* __restrict__ bq,
                                                        const float* __restrict__ bk,
                                                        const float* __restrict__ bv,
                                                        float* __restrict__ out) {
  int i = blockIdx.x * 256 + threadIdx.x;
  if (i >= 3072) return;
  out[i] = (i < 1024) ? bq[i] : (i < 2048 ? bk[i - 1024] : bv[i - 2048]);
}

// ====== m97-style GEMMs: single-buffered LDS, stage -> syncthreads (vmcnt
// ====== drain, cross-wave landed) -> COMPILER-scheduled ds_read + MFMA
// ====== (fine lgkmcnt interleave) -> syncthreads. 3 blocks/CU: cross-block
// ====== wave overlap hides the drain (m114/m97 mechanism, 874-912 TF proven).

// ---------------- gemm128: 128x128 tile (QKV: 768 blk = 3/CU; FF1: 512) ------
#define STG128(P) { _Pragma("unroll") for (int q = 0; q < 4; ++q) { \
    gload_lds16(gA0 + (P) + (size_t)(q * 32) * lda2, sAb + q * 4096 + w * 1024); \
    gload_lds16(gB0 + (P) + (size_t)(q * 32) * ldb2, sBb + q * 4096 + w * 1024); } }

__global__ __launch_bounds__(256, 3) void gemm128(
    const bf16* __restrict__ A, int lda,
    const bf16* __restrict__ Bt, int ldb,
    int N, int K, int nbm, int nbn,
    const float* __restrict__ bias,
    bf16* __restrict__ Cb,
    bf16* __restrict__ Qd, bf16* __restrict__ Kd, bf16* __restrict__ Vd,
    int mode) {
  __shared__ bf16 sA[128][64];
  __shared__ bf16 sB[128][64];
  const int nwg = nbm * nbn;
  const int orig = blockIdx.x;
  const int wgid = (orig % 8) * (nwg / 8) + orig / 8;  // nwg % 8 == 0
  const int bm = wgid / nbn, bn = wgid % nbn;
  const int tid = threadIdx.x;
  const int w = tid >> 6, lane = tid & 63;
  const int wm = w >> 1, wn = w & 1;
  const int ri = lane & 15, kg = lane >> 4;
  const int NT = K / 64;
  const size_t lda2 = (size_t)lda * 2, ldb2 = (size_t)ldb * 2;
  char* sAb = (char*)&sA[0][0];
  char* sBb = (char*)&sB[0][0];

  // compiler-visible swizzled read pointers (fine lgkmcnt scheduling)
  const char* pA[4][2];
  const char* pB[4][2];
#pragma unroll
  for (int i = 0; i < 4; ++i) {
    int row = wm * 64 + i * 16 + ri;
    int swz = (row & 7) << 4;
    pA[i][0] = sAb + row * 128 + ((kg * 16) ^ swz);
    pA[i][1] = sAb + row * 128 + ((64 + kg * 16) ^ swz);
  }
#pragma unroll
  for (int j = 0; j < 4; ++j) {
    int row = wn * 64 + j * 16 + ri;
    int swz = (row & 7) << 4;
    pB[j][0] = sBb + row * 128 + ((kg * 16) ^ swz);
    pB[j][1] = sBb + row * 128 + ((64 + kg * 16) ^ swz);
  }

  const int r0 = tid >> 3;
  const int cb0 = ((tid & 7) * 16) ^ ((r0 & 7) << 4);
  const char* gA0 = (const char*)(A + (size_t)bm * 128 * lda) + (size_t)r0 * lda2 + cb0;
  const char* gB0 = (const char*)(Bt + (size_t)bn * 128 * ldb) + (size_t)r0 * ldb2 + cb0;

  f32x4 acc[4][4] = {};

  size_t koff = 0;
  for (int t = 0; t < NT; ++t) {
    STG128(koff);
    koff += 128;
    __syncthreads();  // vmcnt(0)+lgkmcnt drain: stage landed for ALL waves
    bf16x8 a[4][2], b[4][2];
#pragma unroll
    for (int i = 0; i < 4; ++i) {
      a[i][0] = *(const bf16x8*)pA[i][0];
      a[i][1] = *(const bf16x8*)pA[i][1];
    }
#pragma unroll
    for (int j = 0; j < 4; ++j) {
      b[j][0] = *(const bf16x8*)pB[j][0];
      b[j][1] = *(const bf16x8*)pB[j][1];
    }
#pragma unroll
    for (int i = 0; i < 4; ++i)
#pragma unroll
      for (int j = 0; j < 4; ++j)
#pragma unroll
        for (int kk = 0; kk < 2; ++kk)
          acc[i][j] = __builtin_amdgcn_mfma_f32_16x16x32_bf16(
              a[i][kk], b[j][kk], acc[i][j], 0, 0, 0);
    __syncthreads();  // reads done before next stage overwrites
  }

  const int colbase = bn * 128 + wn * 64 + ri;
  float bv4[4];
#pragma unroll
  for (int nf = 0; nf < 4; ++nf) bv4[nf] = bias[colbase + nf * 16];

  if (mode == EPI_QKV) {
    int col0 = bn * 128 + wn * 64;  // which/hh wave-uniform (64 | 1024)
    int which = col0 >> 10, hh = (col0 >> 6) & 15;
    bf16* dst = (which == 0) ? Qd : (which == 1) ? Kd : Vd;
    float scl = (which == 0) ? QSCL : 1.0f;
#pragma unroll
    for (int mf = 0; mf < 4; ++mf)
#pragma unroll
      for (int r = 0; r < 4; ++r) {
        int row = bm * 128 + wm * 64 + mf * 16 + kg * 4 + r;
        int b2 = row >> 10, s = row & 1023;
        bf16* o = dst + (((size_t)(b2 * 16 + hh)) * 1024 + s) * 64;
#pragma unroll
        for (int nf = 0; nf < 4; ++nf)
          o[nf * 16 + ri] = __float2bfloat16((acc[mf][nf][r] + bv4[nf]) * scl);
      }
  } else {  // EPI_RELU_BF16
#pragma unroll
    for (int mf = 0; mf < 4; ++mf)
#pragma unroll
      for (int r = 0; r < 4; ++r) {
        int row = bm * 128 + wm * 64 + mf * 16 + kg * 4 + r;
        bf16* o = Cb + (size_t)row * N + colbase;
#pragma unroll
        for (int nf = 0; nf < 4; ++nf) {
          float v = acc[mf][nf][r] + bv4[nf];
          o[nf * 16] = __float2bfloat16(v > 0.f ? v : 0.f);
        }
      }
  }
}

// ---------------- gemm64: 128x64 tile for Wo/FF2 (512 blocks, 24KB LDS) ------
#define STG64(P) { \
  _Pragma("unroll") for (int q = 0; q < 4; ++q) \
    gload_lds16(gA0 + (P) + (size_t)(q * 32) * lda2, sAb + q * 4096 + w * 1024); \
  _Pragma("unroll") for (int q = 0; q < 2; ++q) \
    gload_lds16(gB0 + (P) + (size_t)(q * 32) * ldb2, sBb + q * 4096 + w * 1024); }

__global__ __launch_bounds__(256, 3) void gemm64(
    const bf16* __restrict__ A, int lda,
    const bf16* __restrict__ Bt, int ldb,
    int N, int K, int nbm, int nbn,
    const float* __restrict__ bias,
    bf16* __restrict__ Cb) {
  __shared__ bf16 sA[128][64];
  __shared__ bf16 sB[64][64];
  const int nwg = nbm * nbn;
  const int orig = blockIdx.x;
  const int wgid = (orig % 8) * (nwg / 8) + orig / 8;
  const int bm = wgid / nbn, bn = wgid % nbn;
  const int tid = threadIdx.x;
  const int w = tid >> 6, lane = tid & 63;
  const int wm = w >> 1, wn = w & 1;
  const int ri = lane & 15, kg = lane >> 4;
  const int NT = K / 64;
  const size_t lda2 = (size_t)lda * 2, ldb2 = (size_t)ldb * 2;
  char* sAb = (char*)&sA[0][0];
  char* sBb = (char*)&sB[0][0];

  const char* pA[4][2];
  const char* pB[2][2];
#pragma unroll
  for (int i = 0; i < 4; ++i) {
    int row = wm * 64 + i * 16 + ri;
    int swz = (row & 7) << 4;
    pA[i][0] = sAb + row * 128 + ((kg * 16) ^ swz);
    pA[i][1] = sAb + row * 128 + ((64 + kg * 16) ^ swz);
  }
#pragma unroll
  for (int j = 0; j < 2; ++j) {
    int row = wn * 32 + j * 16 + ri;
    int swz = (row & 7) << 4;
    pB[j][0] = sBb + row * 128 + ((kg * 16) ^ swz);
    pB[j][1] = sBb + row * 128 + ((64 + kg * 16) ^ swz);
  }

  const int r0 = tid >> 3;
  const int cb0 = ((tid & 7) * 16) ^ ((r0 & 7) << 4);
  const char* gA0 = (const char*)(A + (size_t)bm * 128 * lda) + (size_t)r0 * lda2 + cb0;
  const char* gB0 = (const char*)(Bt + (size_t)bn * 64 * ldb) + (size_t)r0 * ldb2 + cb0;

  f32x4 acc[4][2] = {};

  size_t koff = 0;
  for (int t = 0; t < NT; ++t) {
    STG64(koff);
    koff += 128;
    __syncthreads();
    bf16x8 a[4][2], b[2][2];
#pragma unroll
    for (int i = 0; i < 4; ++i) {
      a[i][0] = *(const bf16x8*)pA[i][0];
      a[i][1] = *(const bf16x8*)pA[i][1];
    }
#pragma unroll
    for (int j = 0; j < 2; ++j) {
      b[j][0] = *(const bf16x8*)pB[j][0];
      b[j][1] = *(const bf16x8*)pB[j][1];
    }
#pragma unroll
    for (int i = 0; i < 4; ++i)
#pragma unroll
      for (int j = 0; j < 2; ++j)
#pragma unroll
        for (int kk = 0; kk < 2; ++kk)
          acc[i][j] = __builtin_amdgcn_mfma_f32_16x16x32_bf16(
              a[i][kk], b[j][kk], acc[i][j], 0, 0, 0);
    __syncthreads();
  }

  const int colbase = bn * 64 + wn * 32 + ri;
  float bv2[2];
#pragma unroll
  for (int nf = 0; nf < 2; ++nf) bv2[nf] = bias[colbase + nf * 16];
#pragma unroll
  for (int mf = 0; mf < 4; ++mf)
#pragma unroll
    for (int r = 0; r < 4; ++r) {
      int row = bm * 128 + wm * 64 + mf * 16 + kg * 4 + r;
      bf16* o = Cb + (size_t)row * N + colbase;
#pragma unroll
      for (int nf = 0; nf < 2; ++nf)
        o[nf * 16] = __float2bfloat16(acc[mf][nf][r] + bv2[nf]);
    }
}

// ---------------- flash attention (R13, passing, unchanged) ----------
__global__ __launch_bounds__(256, 4) void attn_kernel(
    const bf16* __restrict__ Qb, const bf16* __restrict__ Kb,
    const bf16* __restrict__ Vs, bf16* __restrict__ Ob) {
  __shared__ bf16 KV[2][2][64][64];
  __shared__ bf16 Ps[4][16][64];
  const int orig = blockIdx.x;
  const int blk = (orig & 7) * 128 + (orig >> 3);
  const int bh = blk >> 4, qt = blk & 15;
  const int bb = bh >> 4, hh = bh & 15;
  const int tid = threadIdx.x, w = tid >> 6, lane = tid & 63;
  const int ri = lane & 15, kg = lane >> 4, r8 = lane >> 3;
  const int cb = ((lane & 7) * 16) ^ ((r8 & 7) << 4);
  const unsigned rsw = (unsigned)((ri & 7) << 4);
  const bf16* qp = Qb + (size_t)bh * 65536;
  const bf16* kp = Kb + (size_t)bh * 65536;
  const bf16* vp = Vs + (size_t)bh * 65536;
  const int q0 = qt * 64 + w * 16;
  const int c0 = w * 2, c1 = c0 + 1;

  unsigned offk0 = (unsigned)((kg * 16) ^ (int)rsw);
  unsigned offk1 = (unsigned)((64 + kg * 16) ^ (int)rsw);
  unsigned adF[4][2];
  const unsigned kv0 = ldsoff(&KV[0][0][0][0]);
#pragma unroll
  for (int n = 0; n < 4; ++n) {
    unsigned row = (unsigned)((n * 16 + ri) * 128);
    adF[n][0] = kv0 + row + offk0;
    adF[n][1] = kv0 + row + offk1;
  }
  const unsigned ps0 = ldsoff(&Ps[0][0][0]) + (unsigned)(w * 2048 + ri * 128);
  unsigned adPr[2] = {ps0 + offk0, ps0 + offk1};
  char* pwb = (char*)&Ps[0][0][0] + w * 2048 + ri * 128;
  char* adPw[4];
#pragma unroll
  for (int n = 0; n < 4; ++n)
    adPw[n] = pwb + ((n * 32 + kg * 8) ^ (int)rsw);

  bf16x8 qf[2];
  qf[0] = *(const bf16x8*)(qp + (size_t)(q0 + ri) * 64 + kg * 8);
  qf[1] = *(const bf16x8*)(qp + (size_t)(q0 + ri) * 64 + 32 + kg * 8);

  bf16x8 ones;
#pragma unroll
  for (int e = 0; e < 8; ++e) ones[e] = (short)0x3F80;

  f32x4 oacc[4] = {};
  f32x4 lacc = {};
  float mrun = -1e30f;

#define ASTAGE(T, D) { \
    gload_lds16((const char*)(kp + (size_t)((T) * 64 + c0 * 8 + r8) * 64) + cb, \
                (char*)KV + (D) * 16384 + c0 * 1024); \
    gload_lds16((const char*)(kp + (size_t)((T) * 64 + c1 * 8 + r8) * 64) + cb, \
                (char*)KV + (D) * 16384 + c1 * 1024); \
    gload_lds16((const char*)(vp + (size_t)(c0 * 8 + r8) * 1024 + (T) * 64) + cb, \
                (char*)KV + (D) * 16384 + 8192 + c0 * 1024); \
    gload_lds16((const char*)(vp + (size_t)(c1 * 8 + r8) * 1024 + (T) * 64) + cb, \
                (char*)KV + (D) * 16384 + 8192 + c1 * 1024); }

#define ATILE(KOFF, VOFF, STG_, ENDSYNC) { \
  bf16x8 kf0[4], kf1[4]; \
  _Pragma("unroll") for (int n = 0; n < 4; ++n) { \
    DSRO(kf0[n], adF[n][0], KOFF); \
    DSRO(kf1[n], adF[n][1], KOFF); \
  } \
  STG_; \
  LGKM0; SCHED0; \
  f32x4 sac[4] = {}; \
  _Pragma("unroll") for (int n = 0; n < 4; ++n) { \
    sac[n] = __builtin_amdgcn_mfma_f32_16x16x32_bf16(kf0[n], qf[0], sac[n], 0, 0, 0); \
    sac[n] = __builtin_amdgcn_mfma_f32_16x16x32_bf16(kf1[n], qf[1], sac[n], 0, 0, 0); \
  } \
  float mx[4]; \
  _Pragma("unroll") for (int n = 0; n < 4; ++n) \
    mx[n] = fmaxf(fmaxf(sac[n][0], sac[n][1]), fmaxf(sac[n][2], sac[n][3])); \
  float mt16 = fmaxf(fmaxf(mx[0], mx[1]), fmaxf(mx[2], mx[3])); \
  if (!__all(mt16 - mrun <= 8.f)) { \
    float mrow = fmaxf(mt16, __shfl_xor(mt16, 16)); \
    mrow = fmaxf(mrow, __shfl_xor(mrow, 32)); \
    float mnew = fmaxf(mrun, mrow); \
    float corr = exp2f(mrun - mnew); \
    mrun = mnew; \
    float cr[4]; \
    _Pragma("unroll") for (int r = 0; r < 4; ++r) cr[r] = __shfl(corr, kg * 4 + r); \
    _Pragma("unroll") for (int n = 0; n < 4; ++n) { \
      oacc[n][0] *= cr[0]; oacc[n][1] *= cr[1]; \
      oacc[n][2] *= cr[2]; oacc[n][3] *= cr[3]; \
    } \
    lacc[0] *= cr[0]; lacc[1] *= cr[1]; lacc[2] *= cr[2]; lacc[3] *= cr[3]; \
  } \
  _Pragma("unroll") for (int n = 0; n < 4; ++n) { \
    uint2 pk; \
    pk.x = cvtpk(exp2f(sac[n][0] - mrun), exp2f(sac[n][1] - mrun)); \
    pk.y = cvtpk(exp2f(sac[n][2] - mrun), exp2f(sac[n][3] - mrun)); \
    *(uint2*)adPw[n] = pk; \
  } \
  LGKM0; \
  bf16x8 pf0, pf1, vf0[4], vf1[4]; \
  DSRO(pf0, adPr[0], 0); \
  DSRO(pf1, adPr[1], 0); \
  _Pragma("unroll") for (int n = 0; n < 4; ++n) { \
    DSRO(vf0[n], adF[n][0], VOFF); \
    DSRO(vf1[n], adF[n][1], VOFF); \
  } \
  LGKM0; SCHED0; \
  _Pragma("unroll") for (int n = 0; n < 4; ++n) { \
    oacc[n] = __builtin_amdgcn_mfma_f32_16x16x32_bf16(pf0, vf0[n], oacc[n], 0, 0, 0); \
    oacc[n] = __builtin_amdgcn_mfma_f32_16x16x32_bf16(pf1, vf1[n], oacc[n], 0, 0, 0); \
  } \
  lacc = __builtin_amdgcn_mfma_f32_16x16x32_bf16(pf0, ones, lacc, 0, 0, 0); \
  lacc = __builtin_amdgcn_mfma_f32_16x16x32_bf16(pf1, ones, lacc, 0, 0, 0); \
  ENDSYNC }

#define SYNCT { VM0; __syncthreads(); }

  ASTAGE(0, 0);
  VM0;
  __syncthreads();

  for (int tt = 0; tt < 7; ++tt) {
    const int t2 = tt * 2;
    ATILE(0,     8192,  ASTAGE(t2 + 1, 1), SYNCT)
    ATILE(16384, 24576, ASTAGE(t2 + 2, 0), SYNCT)
  }
  ATILE(0,     8192,  ASTAGE(15, 1), SYNCT)
  ATILE(16384, 24576, ,              )

  float ivr[4];
#pragma unroll
  for (int r = 0; r < 4; ++r) ivr[r] = 1.f / lacc[r];
#pragma unroll
  for (int r = 0; r < 4; ++r) {
    int s = q0 + kg * 4 + r;
    size_t base = ((size_t)(bb * 1024 + s)) * 1024 + hh * 64;
#pragma unroll
    for (int n = 0; n < 4; ++n)
      Ob[base + n * 16 + ri] = __float2bfloat16(oacc[n][r] * ivr[r]);
  }
#undef ASTAGE
#undef ATILE
#undef SYNCT
}

// ---------------- fused residual + LayerNorm (bf16 in; bf16 and/or f32 out) ---
__global__ __launch_bounds__(256) void ln_bb(
    const bf16* __restrict__ a, const bf16* __restrict__ b,
    const float* __restrict__ gamma, const float* __restrict__ beta,
    float* __restrict__ out_f32, bf16* __restrict__ out_bf16) {
  int row = blockIdx.x;
  int tid = threadIdx.x;
  ushort4 au = ((const ushort4*)(a + (size_t)row * 1024))[tid];
  ushort4 bu = ((const ushort4*)(b + (size_t)row * 1024))[tid];
  float4 z;
  z.x = bu2f(au.x) + bu2f(bu.x);
  z.y = bu2f(au.y) + bu2f(bu.y);
  z.z = bu2f(au.z) + bu2f(bu.z);
  z.w = bu2f(au.w) + bu2f(bu.w);
  float s = z.x + z.y + z.z + z.w;
  float ss = z.x * z.x + z.y * z.y + z.z * z.z + z.w * z.w;
#pragma unroll
  for (int o = 32; o >= 1; o >>= 1) { s += __shfl_xor(s, o); ss += __shfl_xor(ss, o); }
  __shared__ float red[8];
  int wid = tid >> 6;
  if ((tid & 63) == 0) { red[wid] = s; red[4 + wid] = ss; }
  __syncthreads();
  s = red[0] + red[1] + red[2] + red[3];
  ss = red[4] + red[5] + red[6] + red[7];
  float mean = s * (1.f / 1024.f);
  float var = ss * (1.f / 1024.f) - mean * mean;
  var = var > 0.f ? var : 0.f;
  float inv = 1.f / (sqrtf(var) + EPS_LN);
  float4 g = ((const float4*)gamma)[tid];
  float4 be = ((const float4*)beta)[tid];
  float4 y;
  y.x = (z.x - mean) * inv * g.x + be.x;
  y.y = (z.y - mean) * inv * g.y + be.y;
  y.z = (z.z - mean) * inv * g.z + be.z;
  y.w = (z.w - mean) * inv * g.w + be.w;
  if (out_f32)
    ((float4*)(out_f32 + (size_t)row * 1024))[tid] = y;
  if (out_bf16) {
    ushort4 o;
    o.x = f2bfu(y.x); o.y = f2bfu(y.y); o.z = f2bfu(y.z); o.w = f2bfu(y.w);
    ((ushort4*)(out_bf16 + (size_t)row * 1024))[tid] = o;
  }
}

// ---------------- launch ----------------
extern "C" void kernel_launch(void* const* d_in, const int* in_sizes, int n_in,
                              void* d_out, int out_size, void* d_ws, size_t ws_size,
                              hipStream_t stream) {
  const float* x = (const float*)d_in[0];
  const float* wq = (const float*)d_in[1];
  const float* bq = (const float*)d_in[2];
  const float* wk = (const float*)d_in[3];
  const float* bk = (const float*)d_in[4];
  const float* wv = (const float*)d_in[5];
  const float* bv = (const float*)d_in[6];
  const float* wo_w = (const float*)d_in[7];
  const float* wo_b = (const float*)d_in[8];
  const float* g1 = (const float*)d_in[9];
  const float* b1 = (const float*)d_in[10];
  const float* ff1w = (const float*)d_in[11];
  const float* ff1b = (const float*)d_in[12];
  const float* ff2w = (const float*)d_in[13];
  const float* ff2b = (const float*)d_in[14];
  const float* g2 = (const float*)d_in[15];
  const float* b2 = (const float*)d_in[16];

  char* ws = (char*)d_ws;
  size_t off = 0;
  auto alloc = [&](size_t bytes) {
    char* p = ws + off;
    off += (bytes + 255) & ~(size_t)255;
    return p;
  };
  bf16* xb = (bf16*)alloc((size_t)NTOK * 1024 * 2);
  bf16* wqkvt = (bf16*)alloc((size_t)3072 * 1024 * 2);
  bf16* wot = (bf16*)alloc((size_t)1024 * 1024 * 2);
  bf16* ff1t = (bf16*)alloc((size_t)2048 * 1024 * 2);
  bf16* ff2t = (bf16*)alloc((size_t)1024 * 2048 * 2);
  float* qkvbias = (float*)alloc(3072 * 4);
  bf16* qbuf = (bf16*)alloc((size_t)64 * 1024 * 64 * 2);
  bf16* kbuf = (bf16*)alloc((size_t)64 * 1024 * 64 * 2);
  bf16* vbuf = (bf16*)alloc((size_t)64 * 1024 * 64 * 2);
  bf16* vtb = (bf16*)alloc((size_t)64 * 64 * 1024 * 2);
  bf16* attnb = (bf16*)alloc((size_t)NTOK * 1024 * 2);
  bf16* projb = (bf16*)alloc((size_t)NTOK * 1024 * 2);
  bf16* hb = (bf16*)alloc((size_t)NTOK * 1024 * 2);
  bf16* ff1o = qbuf;  // reuse q+k region (dead after attention)

  // prep
  cvt_bf16_kernel<<<(NTOK * 1024 / 4 + 255) / 256, 256, 0, stream>>>(x, xb, NTOK * 1024 / 4);
  transpose_cvt<float><<<dim3(2, 32, 16), 256, 0, stream>>>(wq, wqkvt, 1024, 64);
  transpose_cvt<float><<<dim3(2, 32, 16), 256, 0, stream>>>(wk, wqkvt + 1024 * 1024, 1024, 64);
  transpose_cvt<float><<<dim3(2, 32, 16), 256, 0, stream>>>(wv, wqkvt + 2 * 1024 * 1024, 1024, 64);
  transpose_cvt<float><<<dim3(32, 32, 1), 256, 0, stream>>>(wo_w, wot, 1024, 1024);
  transpose_cvt<float><<<dim3(64, 32, 1), 256, 0, stream>>>(ff1w, ff1t, 1024, 2048);
  transpose_cvt<float><<<dim3(32, 64, 1), 256, 0, stream>>>(ff2w, ff2t, 2048, 1024);
  pack_bias_kernel<<<12, 256, 0, stream>>>(bq, bk, bv, qkvbias);

  // QKV: 128x128 m97-style -> 768 blocks = 3/CU exact
  gemm128<<<768, 256, 0, stream>>>(xb, 1024, wqkvt, 1024, 3072, 1024, 32, 24,
                                   qkvbias, nullptr, qbuf, kbuf, vbuf, EPI_QKV);
  // V -> V^T per (b,h)
  transpose_cvt<bf16><<<dim3(2, 32, 64), 256, 0, stream>>>(vbuf, vtb, 1024, 64);
  // attention
  attn_kernel<<<dim3(1024), 256, 0, stream>>>(qbuf, kbuf, vtb, attnb);
  // Wo: 128x64 m97-style -> 512 blocks
  gemm64<<<512, 256, 0, stream>>>(attnb, 1024, wot, 1024, 1024, 1024, 32, 16,
                                  wo_b, projb);
  // LN1: h = LN(xb + projb) -> hb (bf16 only)
  ln_bb<<<4096, 256, 0, stream>>>(xb, projb, g1, b1, nullptr, hb);
  // FF1 + ReLU: 128x128 m97-style -> 512 blocks
  gemm128<<<512, 256, 0, stream>>>(hb, 1024, ff1t, 1024, 2048, 1024, 32, 16,
                                   ff1b, ff1o, nullptr, nullptr, nullptr, EPI_RELU_BF16);
  // FF2: 128x64 m97-style, K=2048 -> 512 blocks
  gemm64<<<512, 256, 0, stream>>>(ff1o, 2048, ff2t, 2048, 1024, 2048, 32, 16,
                                  ff2b, projb);
  // LN2: out = LN(hb + projb) -> d_out (f32)
  ln_bb<<<4096, 256, 0, stream>>>(hb, projb, g2, b2, (float*)d_out, nullptr);
}